// Round 1
// baseline (652.951 us; speedup 1.0000x reference)
//
#include <hip/hip_runtime.h>

#define NTAGS 48
#define NB    512
#define SLEN  2048

// ---------- cross-lane helpers (wave64, DPP) ----------

__device__ __forceinline__ float rl_f(float v, int l) {
  return __builtin_bit_cast(float, __builtin_amdgcn_readlane(__builtin_bit_cast(int, v), l));
}

template <int CTRL, bool BC>
__device__ __forceinline__ float dpp_mv(float oldv, float v) {
  return __builtin_bit_cast(float, __builtin_amdgcn_update_dpp(
      __builtin_bit_cast(int, oldv), __builtin_bit_cast(int, v), CTRL, 0xF, 0xF, BC));
}

__device__ __forceinline__ float wred_max(float v) {
  v = fmaxf(v, dpp_mv<0x128, false>(v, v));
  v = fmaxf(v, dpp_mv<0x124, false>(v, v));
  v = fmaxf(v, dpp_mv<0x122, false>(v, v));
  v = fmaxf(v, dpp_mv<0x121, false>(v, v));
  v = fmaxf(v, dpp_mv<0x142, false>(v, v));
  v = fmaxf(v, dpp_mv<0x143, false>(v, v));
  return rl_f(v, 63);
}

__device__ __forceinline__ float wred_sum(float v) {
  v += dpp_mv<0x128, true>(0.0f, v);
  v += dpp_mv<0x124, true>(0.0f, v);
  v += dpp_mv<0x122, true>(0.0f, v);
  v += dpp_mv<0x121, true>(0.0f, v);
  v += dpp_mv<0x142, true>(0.0f, v);
  v += dpp_mv<0x143, true>(0.0f, v);
  return rl_f(v, 63);
}

// broadcast-dot via LDS: all 64 lanes read the same 48 floats.
// Same-address LDS reads are a hardware broadcast (no bank conflict), so
// 12x ds_read_b128 (+1 ds_write_b32 by the caller) replaces 48 v_readlane
// on the VALU issue pipe. fmaf order/indices identical to the old rdot48
// -> bitwise-identical result.
__device__ __forceinline__ float ldot48(const float* pvp, const float* Ev) {
  const float4* p4 = (const float4*)pvp;
  float4 c[12];
#pragma unroll
  for (int k = 0; k < 12; ++k) c[k] = p4[k];   // 12x ds_read_b128, issued early
  float a0 = 0.f, a1 = 0.f, a2 = 0.f, a3 = 0.f;
#pragma unroll
  for (int k = 0; k < 12; ++k) {
    a0 = fmaf(c[k].x, Ev[4 * k + 0], a0);
    a1 = fmaf(c[k].y, Ev[4 * k + 1], a1);
    a2 = fmaf(c[k].z, Ev[4 * k + 2], a2);
    a3 = fmaf(c[k].w, Ev[4 * k + 3], a3);
  }
  return (a0 + a1) + (a2 + a3);
}

// exact pow2 renorm: p *= 2^-e, cl += e*ln2
__device__ __forceinline__ void renorm(float& p, float& cl) {
  float mx = wred_max(p);
  int e = ((__builtin_bit_cast(int, mx) >> 23) & 255) - 127;
  float r = __builtin_bit_cast(float, (127 - e) << 23);
  p *= r;
  cl += (float)e * 0.6931471805599453f;
}

// ---------- fused kernel ----------
// blocks [0,1024): scan. even = forward half (alpha_1024), odd = backward half (beta_1024).
// blocks [1024,1536): gold-path score + mask count, one wave per batch.

extern "C" __global__ __launch_bounds__(64, 1)
void crf_main(const float* __restrict__ emis,
              const float* __restrict__ trans,
              const float* __restrict__ startt,
              const float* __restrict__ endt,
              const int*   __restrict__ tags,
              const float* __restrict__ mask,
              float* __restrict__ wa, float* __restrict__ wb,
              float* __restrict__ wsc, int* __restrict__ wcnt) {
  __shared__ float st[NTAGS * NTAGS];
  __shared__ __align__(16) float pv[64];   // per-step broadcast buffer (48 live + 16 pad)
  const int lane = threadIdx.x;
  const int bid  = blockIdx.x;

  if (bid >= 2 * NB) {
    // ----- score path -----
    const int b = bid - 2 * NB;
    for (int k = lane; k < NTAGS * NTAGS; k += 64) st[k] = trans[k];
    __syncthreads();
    const int* tb = tags + (size_t)b * SLEN;
    float ssum = 0.0f, csum = 0.0f;
    for (int it = 0; it < SLEN / 64; ++it) {
      const int t   = it * 64 + lane;
      int   cur = tb[t];
      float mv  = mask[(size_t)b * SLEN + t];
      float ev  = emis[((size_t)b * SLEN + t) * NTAGS + cur];
      float s;
      if (t == 0) {
        s = startt[cur] + ev;  // unmasked per reference
      } else {
        int prev = tb[t - 1];
        s = (mv != 0.0f) ? (st[prev * NTAGS + cur] + ev) : 0.0f;
      }
      ssum += s;
      csum += (mv != 0.0f) ? 1.0f : 0.0f;
    }
    ssum = wred_sum(ssum);
    csum = wred_sum(csum);
    if (lane == 0) { wsc[b] = ssum; wcnt[b] = (int)(csum + 0.5f); }
    return;
  }

  // ----- scan path -----
  const int  b   = bid >> 1;
  const bool fwd = (bid & 1) == 0;
  const int  jc  = lane < NTAGS ? lane : (NTAGS - 1);  // pad lanes mirror lane 47

  const float* eb = emis + (size_t)b * SLEN * NTAGS;
  const float* mb = mask + (size_t)b * SLEN;

  // opaque zero in a VGPR: forces mask loads onto the vector-memory path
  // (vmcnt) so the inner loop has NO scalar loads -> lgkmcnt counts DS only
  // and the compiler can emit precise fine-grained lgkmcnt(N) waits.
  int zr = 0;
  asm volatile("" : "+v"(zr));

  float* myslot = pv + lane;  // fixed ds_write address

  float Ev[NTAGS];  // fwd: lane j holds column j of exp(trans); bwd: lane i holds row i
  if (fwd) {
#pragma unroll
    for (int i = 0; i < NTAGS; ++i) Ev[i] = __expf(trans[i * NTAGS + jc]);
  } else {
#pragma unroll
    for (int j = 0; j < NTAGS; ++j) Ev[j] = __expf(trans[jc * NTAGS + j]);
  }

  float ebuf[8];  // 8-deep emission prefetch ring, slot = t & 7
  float p, cl, een;

  if (fwd) {
    float a0 = startt[jc] + eb[jc];
    if (lane >= NTAGS) a0 = -1e30f;
    float m0 = wred_max(a0);
    p  = __expf(a0 - m0);   // pad lanes duplicate lane 47's column -> p_pad == p_47, harmless
    cl = m0;
#pragma unroll
    for (int k = 1; k <= 8; ++k) ebuf[k & 7] = eb[(size_t)k * NTAGS + jc];
    een = __expf(ebuf[1]);  // exp(emit_1)

    for (int g = 0; g < 128; ++g) {
#pragma unroll
      for (int u = 0; u < 8; ++u) {
        const int t = 1 + 8 * g + u;
        float ee = een;                       // exp(emit_t), off-chain
        een = __expf(ebuf[(t + 1) & 7]);
        *myslot = p;                          // ds_write_b32 (lanes 48..63 -> pad slots)
        asm volatile("" ::: "memory");        // order: write before this step's reads
        float acc = ldot48(pv, Ev);           // alpha-hat via LDS broadcast
        float mv  = mb[t + zr];               // vector load, vmcnt
        float pn  = acc * ee;
        p = (mv != 0.0f) ? pn : p;
        ebuf[t & 7] = eb[(size_t)(t + 8) * NTAGS + jc];  // prefetch t+8
        if (u == 7) renorm(p, cl);
      }
    }
    if (lane < NTAGS) wa[b * NTAGS + lane] = __logf(p) + cl;
  } else {
    float b0 = endt[jc];
    if (lane >= NTAGS) b0 = -1e30f;
    float m0 = wred_max(b0);
    p  = __expf(b0 - m0);
    cl = m0;
#pragma unroll
    for (int k = 0; k < 8; ++k) ebuf[(2047 - k) & 7] = eb[(size_t)(2047 - k) * NTAGS + jc];
    float q = p * __expf(ebuf[7]);  // q_2047 = beta_2047 * exp(emit_2047)
    een = __expf(ebuf[6]);          // exp(emit_2046)

    // peel t = 2047..2041 to align groups of 8
#pragma unroll
    for (int pt = 0; pt < 7; ++pt) {
      const int t = 2047 - pt;
      float ee = een;                       // exp(emit_{t-1})
      een = __expf(ebuf[(t + 6) & 7]);      // emit_{t-2}
      *myslot = q;
      asm volatile("" ::: "memory");
      float acc = ldot48(pv, Ev);           // beta_{t-1}
      float mv  = mb[t + zr];
      p = (mv != 0.0f) ? acc : p;
      ebuf[t & 7] = eb[(size_t)(t - 8) * NTAGS + jc];
      if (pt == 6) renorm(p, cl);
      q = p * ee;
    }
    for (int g = 0; g < 127; ++g) {
#pragma unroll
      for (int u = 0; u < 8; ++u) {
        const int t = 2040 - 8 * g - u;     // down to 1025
        float ee = een;
        een = __expf(ebuf[(t + 6) & 7]);
        *myslot = q;
        asm volatile("" ::: "memory");
        float acc = ldot48(pv, Ev);
        float mv  = mb[t + zr];
        p = (mv != 0.0f) ? acc : p;
        ebuf[t & 7] = eb[(size_t)(t - 8) * NTAGS + jc];
        if (u == 7) renorm(p, cl);
        q = p * ee;
      }
    }
    if (lane < NTAGS) wb[b * NTAGS + lane] = __logf(p) + cl;
  }
}

// ---------- combine: partition_b = lse(alpha_1024 + beta_1024); loss ----------

extern "C" __global__ __launch_bounds__(64)
void crf_combine(const float* __restrict__ wa, const float* __restrict__ wb,
                 const float* __restrict__ wsc, const int* __restrict__ wcnt,
                 const int* __restrict__ tags, const float* __restrict__ endt,
                 float* __restrict__ out) {
  const int b    = blockIdx.x;
  const int lane = threadIdx.x;
  float v = -1e30f;
  if (lane < NTAGS) v = wa[b * NTAGS + lane] + wb[b * NTAGS + lane];
  float m = wred_max(v);
  float s = wred_sum(__expf(v - m));
  float part = m + __logf(s);
  int   last = wcnt[b] - 1;
  float score = wsc[b] + endt[tags[(size_t)b * SLEN + last]];
  if (lane == 0) atomicAdd(out, (part - score) * (1.0f / (float)NB));
}

// ---------- launch ----------

extern "C" void kernel_launch(void* const* d_in, const int* in_sizes, int n_in,
                              void* d_out, int out_size, void* d_ws, size_t ws_size,
                              hipStream_t stream) {
  const float* emis  = (const float*)d_in[0];
  const float* trans = (const float*)d_in[1];
  const float* stt   = (const float*)d_in[2];
  const float* ent   = (const float*)d_in[3];
  const int*   tags  = (const int*)d_in[4];
  const float* mask  = (const float*)d_in[5];

  float* wa   = (float*)d_ws;            // [NB][NTAGS]
  float* wb   = wa + NB * NTAGS;         // [NB][NTAGS]
  float* wsc  = wb + NB * NTAGS;         // [NB]
  int*   wcnt = (int*)(wsc + NB);        // [NB]

  hipMemsetAsync(d_out, 0, sizeof(float), stream);
  crf_main<<<2 * NB + NB, 64, 0, stream>>>(emis, trans, stt, ent, tags, mask,
                                           wa, wb, wsc, wcnt);
  crf_combine<<<NB, 64, 0, stream>>>(wa, wb, wsc, wcnt, tags, ent, (float*)d_out);
}

// Round 2
// 421.288 us; speedup vs baseline: 1.5499x; 1.5499x over previous
//
#include <hip/hip_runtime.h>

#define NTAGS 48
#define NB    512
#define SLEN  2048

typedef float f32x2 __attribute__((ext_vector_type(2)));

// ---------- cross-lane helpers (wave64, DPP) ----------

__device__ __forceinline__ float rl_f(float v, int l) {
  return __builtin_bit_cast(float, __builtin_amdgcn_readlane(__builtin_bit_cast(int, v), l));
}

template <int CTRL, bool BC>
__device__ __forceinline__ float dpp_mv(float oldv, float v) {
  return __builtin_bit_cast(float, __builtin_amdgcn_update_dpp(
      __builtin_bit_cast(int, oldv), __builtin_bit_cast(int, v), CTRL, 0xF, 0xF, BC));
}

__device__ __forceinline__ float wred_max(float v) {
  v = fmaxf(v, dpp_mv<0x128, false>(v, v));
  v = fmaxf(v, dpp_mv<0x124, false>(v, v));
  v = fmaxf(v, dpp_mv<0x122, false>(v, v));
  v = fmaxf(v, dpp_mv<0x121, false>(v, v));
  v = fmaxf(v, dpp_mv<0x142, false>(v, v));
  v = fmaxf(v, dpp_mv<0x143, false>(v, v));
  return rl_f(v, 63);
}

__device__ __forceinline__ float wred_sum(float v) {
  v += dpp_mv<0x128, true>(0.0f, v);
  v += dpp_mv<0x124, true>(0.0f, v);
  v += dpp_mv<0x122, true>(0.0f, v);
  v += dpp_mv<0x121, true>(0.0f, v);
  v += dpp_mv<0x142, true>(0.0f, v);
  v += dpp_mv<0x143, true>(0.0f, v);
  return rl_f(v, 63);
}

// broadcast-dot: y = sum_{i<48} p[i] * Ev[i].
// readlanes write hardcoded SGPRs so v_pk_fma_f32 can consume s[2k:2k+1]
// directly as its packed scalar operand (no SALU packing, no VGPR movs).
// 48 RL + 24 PK per step vs r0's 48 RL + 48 FMAC.
// Accumulator pairing: a01.x<-tags 4k+0, a01.y<-4k+1, a23.x<-4k+2,
// a23.y<-4k+3; final (a0+a1)+(a2+a3) -> bitwise-identical to r0's rdot48.
// Hazard note: >=1 instruction separates each v_readlane SGPR write from
// the v_pk_fma that reads it.
#define DOT4(L0, L1, L2, L3, E01, E23, SA, SB, SC, SD, PA, PB)              \
  asm("v_readlane_b32 " SA ", %2, " #L0 "\n\t"                              \
      "v_readlane_b32 " SB ", %2, " #L1 "\n\t"                              \
      "v_readlane_b32 " SC ", %2, " #L2 "\n\t"                              \
      "v_readlane_b32 " SD ", %2, " #L3 "\n\t"                              \
      "v_pk_fma_f32 %0, " PA ", %3, %0\n\t"                                 \
      "v_pk_fma_f32 %1, " PB ", %4, %1"                                     \
      : "+v"(a01), "+v"(a23)                                                \
      : "v"(pv), "v"(E01), "v"(E23)                                         \
      : "s80", "s81", "s82", "s83", "s84", "s85", "s86", "s87")

__device__ __forceinline__ float pkdot48(float pval, const f32x2* Ev2) {
  const int pv = __builtin_bit_cast(int, pval);
  f32x2 a01 = {0.0f, 0.0f};
  f32x2 a23 = {0.0f, 0.0f};
  DOT4(0, 1, 2, 3,     Ev2[0],  Ev2[1],  "s80","s81","s82","s83","s[80:81]","s[82:83]");
  DOT4(4, 5, 6, 7,     Ev2[2],  Ev2[3],  "s84","s85","s86","s87","s[84:85]","s[86:87]");
  DOT4(8, 9, 10, 11,   Ev2[4],  Ev2[5],  "s80","s81","s82","s83","s[80:81]","s[82:83]");
  DOT4(12, 13, 14, 15, Ev2[6],  Ev2[7],  "s84","s85","s86","s87","s[84:85]","s[86:87]");
  DOT4(16, 17, 18, 19, Ev2[8],  Ev2[9],  "s80","s81","s82","s83","s[80:81]","s[82:83]");
  DOT4(20, 21, 22, 23, Ev2[10], Ev2[11], "s84","s85","s86","s87","s[84:85]","s[86:87]");
  DOT4(24, 25, 26, 27, Ev2[12], Ev2[13], "s80","s81","s82","s83","s[80:81]","s[82:83]");
  DOT4(28, 29, 30, 31, Ev2[14], Ev2[15], "s84","s85","s86","s87","s[84:85]","s[86:87]");
  DOT4(32, 33, 34, 35, Ev2[16], Ev2[17], "s80","s81","s82","s83","s[80:81]","s[82:83]");
  DOT4(36, 37, 38, 39, Ev2[18], Ev2[19], "s84","s85","s86","s87","s[84:85]","s[86:87]");
  DOT4(40, 41, 42, 43, Ev2[20], Ev2[21], "s80","s81","s82","s83","s[80:81]","s[82:83]");
  DOT4(44, 45, 46, 47, Ev2[22], Ev2[23], "s84","s85","s86","s87","s[84:85]","s[86:87]");
  return (a01.x + a01.y) + (a23.x + a23.y);
}

// exact pow2 renorm: p *= 2^-e, cl += e*ln2
__device__ __forceinline__ void renorm(float& p, float& cl) {
  float mx = wred_max(p);
  int e = ((__builtin_bit_cast(int, mx) >> 23) & 255) - 127;
  float r = __builtin_bit_cast(float, (127 - e) << 23);
  p *= r;
  cl += (float)e * 0.6931471805599453f;
}

// ---------- fused kernel ----------
// blocks [0,1024): scan. even = forward half (alpha_1024), odd = backward half (beta_1024).
// blocks [1024,1536): gold-path score + mask count, one wave per batch.

extern "C" __global__ __launch_bounds__(64, 1)
void crf_main(const float* __restrict__ emis,
              const float* __restrict__ trans,
              const float* __restrict__ startt,
              const float* __restrict__ endt,
              const int*   __restrict__ tags,
              const float* __restrict__ mask,
              float* __restrict__ wa, float* __restrict__ wb,
              float* __restrict__ wsc, int* __restrict__ wcnt) {
  __shared__ float st[NTAGS * NTAGS];
  const int lane = threadIdx.x;
  const int bid  = blockIdx.x;

  if (bid >= 2 * NB) {
    // ----- score path -----
    const int b = bid - 2 * NB;
    for (int k = lane; k < NTAGS * NTAGS; k += 64) st[k] = trans[k];
    __syncthreads();
    const int* tb = tags + (size_t)b * SLEN;
    float ssum = 0.0f, csum = 0.0f;
    for (int it = 0; it < SLEN / 64; ++it) {
      const int t   = it * 64 + lane;
      int   cur = tb[t];
      float mv  = mask[(size_t)b * SLEN + t];
      float ev  = emis[((size_t)b * SLEN + t) * NTAGS + cur];
      float s;
      if (t == 0) {
        s = startt[cur] + ev;  // unmasked per reference
      } else {
        int prev = tb[t - 1];
        s = (mv != 0.0f) ? (st[prev * NTAGS + cur] + ev) : 0.0f;
      }
      ssum += s;
      csum += (mv != 0.0f) ? 1.0f : 0.0f;
    }
    ssum = wred_sum(ssum);
    csum = wred_sum(csum);
    if (lane == 0) { wsc[b] = ssum; wcnt[b] = (int)(csum + 0.5f); }
    return;
  }

  // ----- scan path -----
  const int  b   = bid >> 1;
  const bool fwd = (bid & 1) == 0;
  const int  jc  = lane < NTAGS ? lane : (NTAGS - 1);  // pad lanes mirror lane 47

  const float* eb = emis + (size_t)b * SLEN * NTAGS;
  const float* mb = mask + (size_t)b * SLEN;

  f32x2 Ev2[24];  // fwd: lane j holds column j of exp(trans); bwd: lane i holds row i
  if (fwd) {
#pragma unroll
    for (int i = 0; i < NTAGS; i += 2) {
      Ev2[i / 2].x = __expf(trans[(i + 0) * NTAGS + jc]);
      Ev2[i / 2].y = __expf(trans[(i + 1) * NTAGS + jc]);
    }
  } else {
#pragma unroll
    for (int j = 0; j < NTAGS; j += 2) {
      Ev2[j / 2].x = __expf(trans[jc * NTAGS + j + 0]);
      Ev2[j / 2].y = __expf(trans[jc * NTAGS + j + 1]);
    }
  }

  float ebuf[8];  // 8-deep emission prefetch ring, slot = t & 7
  float p, cl, een;

  if (fwd) {
    float mnext = mb[1 + (lane & 7)];  // masks for group 0 (bits 0..7 of ballot)
    float a0 = startt[jc] + eb[jc];
    if (lane >= NTAGS) a0 = -1e30f;
    float m0 = wred_max(a0);
    p  = __expf(a0 - m0);   // pad lanes duplicate lane 47's column -> p_pad == p_47, harmless
    cl = m0;
#pragma unroll
    for (int k = 1; k <= 8; ++k) ebuf[k & 7] = eb[(size_t)k * NTAGS + jc];
    een = __expf(ebuf[1]);  // exp(emit_1)

    for (int g = 0; g < 128; ++g) {
      const int t0 = 1 + 8 * g;
      const uint32_t m8 = (uint32_t)__ballot(mnext != 0.0f) & 0xffu;
      mnext = mb[(size_t)(t0 + 8) + (lane & 7)];   // prefetch next group's masks
      if (m8 == 0xffu) {
        // fast path: all masked-in, no select on the chain
#pragma unroll
        for (int u = 0; u < 8; ++u) {
          const int t = t0 + u;
          float ee = een;                       // exp(emit_t), off-chain
          een = __expf(ebuf[(t + 1) & 7]);
          float acc = pkdot48(p, Ev2);
          p = acc * ee;
          ebuf[t & 7] = eb[(size_t)(t + 8) * NTAGS + jc];  // prefetch t+8
          if (u == 7) renorm(p, cl);
        }
      } else {
#pragma unroll
        for (int u = 0; u < 8; ++u) {
          const int t = t0 + u;
          float ee = een;
          een = __expf(ebuf[(t + 1) & 7]);
          float acc = pkdot48(p, Ev2);
          float pn  = acc * ee;
          p = ((m8 >> u) & 1u) ? pn : p;
          ebuf[t & 7] = eb[(size_t)(t + 8) * NTAGS + jc];
          if (u == 7) renorm(p, cl);
        }
      }
    }
    if (lane < NTAGS) wa[b * NTAGS + lane] = __logf(p) + cl;
  } else {
    float mnext = mb[2040 - (lane & 7)];  // masks for group 0 of main loop
    float b0 = endt[jc];
    if (lane >= NTAGS) b0 = -1e30f;
    float m0 = wred_max(b0);
    p  = __expf(b0 - m0);
    cl = m0;
#pragma unroll
    for (int k = 0; k < 8; ++k) ebuf[(2047 - k) & 7] = eb[(size_t)(2047 - k) * NTAGS + jc];
    float q = p * __expf(ebuf[7]);  // q_2047 = beta_2047 * exp(emit_2047)
    een = __expf(ebuf[6]);          // exp(emit_2046)

    // peel t = 2047..2041 to align groups of 8 (mask via per-step loads; off hot path)
#pragma unroll
    for (int pt = 0; pt < 7; ++pt) {
      const int t = 2047 - pt;
      float ee = een;                       // exp(emit_{t-1})
      een = __expf(ebuf[(t + 6) & 7]);      // emit_{t-2}
      float acc = pkdot48(q, Ev2);          // beta_{t-1}
      float mv  = mb[t];
      p = (mv != 0.0f) ? acc : p;
      ebuf[t & 7] = eb[(size_t)(t - 8) * NTAGS + jc];
      if (pt == 6) renorm(p, cl);
      q = p * ee;
    }
    for (int g = 0; g < 127; ++g) {
      const int t0 = 2040 - 8 * g;
      const uint32_t m8 = (uint32_t)__ballot(mnext != 0.0f) & 0xffu;  // bit u <-> t0-u
      mnext = mb[(size_t)(t0 - 8) - (lane & 7)];
      if (m8 == 0xffu) {
#pragma unroll
        for (int u = 0; u < 8; ++u) {
          const int t = t0 - u;               // down to 1025
          float ee = een;
          een = __expf(ebuf[(t + 6) & 7]);
          float acc = pkdot48(q, Ev2);
          p = acc;
          ebuf[t & 7] = eb[(size_t)(t - 8) * NTAGS + jc];
          if (u == 7) renorm(p, cl);
          q = p * ee;
        }
      } else {
#pragma unroll
        for (int u = 0; u < 8; ++u) {
          const int t = t0 - u;
          float ee = een;
          een = __expf(ebuf[(t + 6) & 7]);
          float acc = pkdot48(q, Ev2);
          p = ((m8 >> u) & 1u) ? acc : p;
          ebuf[t & 7] = eb[(size_t)(t - 8) * NTAGS + jc];
          if (u == 7) renorm(p, cl);
          q = p * ee;
        }
      }
    }
    if (lane < NTAGS) wb[b * NTAGS + lane] = __logf(p) + cl;
  }
}

// ---------- combine: partition_b = lse(alpha_1024 + beta_1024); loss ----------

extern "C" __global__ __launch_bounds__(64)
void crf_combine(const float* __restrict__ wa, const float* __restrict__ wb,
                 const float* __restrict__ wsc, const int* __restrict__ wcnt,
                 const int* __restrict__ tags, const float* __restrict__ endt,
                 float* __restrict__ out) {
  const int b    = blockIdx.x;
  const int lane = threadIdx.x;
  float v = -1e30f;
  if (lane < NTAGS) v = wa[b * NTAGS + lane] + wb[b * NTAGS + lane];
  float m = wred_max(v);
  float s = wred_sum(__expf(v - m));
  float part = m + __logf(s);
  int   last = wcnt[b] - 1;
  float score = wsc[b] + endt[tags[(size_t)b * SLEN + last]];
  if (lane == 0) atomicAdd(out, (part - score) * (1.0f / (float)NB));
}

// ---------- launch ----------

extern "C" void kernel_launch(void* const* d_in, const int* in_sizes, int n_in,
                              void* d_out, int out_size, void* d_ws, size_t ws_size,
                              hipStream_t stream) {
  const float* emis  = (const float*)d_in[0];
  const float* trans = (const float*)d_in[1];
  const float* stt   = (const float*)d_in[2];
  const float* ent   = (const float*)d_in[3];
  const int*   tags  = (const int*)d_in[4];
  const float* mask  = (const float*)d_in[5];

  float* wa   = (float*)d_ws;            // [NB][NTAGS]
  float* wb   = wa + NB * NTAGS;         // [NB][NTAGS]
  float* wsc  = wb + NB * NTAGS;         // [NB]
  int*   wcnt = (int*)(wsc + NB);        // [NB]

  hipMemsetAsync(d_out, 0, sizeof(float), stream);
  crf_main<<<2 * NB + NB, 64, 0, stream>>>(emis, trans, stt, ent, tags, mask,
                                           wa, wb, wsc, wcnt);
  crf_combine<<<NB, 64, 0, stream>>>(wa, wb, wsc, wcnt, tags, ent, (float*)d_out);
}